// Round 12
// baseline (197.921 us; speedup 1.0000x reference)
//
#include <hip/hip_runtime.h>
#include <hip/hip_bf16.h>
#include <math.h>

typedef __attribute__((ext_vector_type(8))) short short8;
typedef __attribute__((ext_vector_type(4))) float floatx4;

static __device__ __forceinline__ unsigned short f2bf(float f) {
    union { float f; unsigned int u; } a; a.f = f;
    unsigned int u = a.u;
    return (unsigned short)((u + 0x7FFFu + ((u >> 16) & 1u)) >> 16);
}
static __device__ __forceinline__ float bf2f(unsigned short h) {
    union { unsigned int u; float f; } a; a.u = ((unsigned int)h) << 16;
    return a.f;
}

// ---------------- fp32 -> bf16 convert, 8 elems/thread ----------------
static __device__ __forceinline__ void cvt8(const float* __restrict__ src,
                                            unsigned short* __restrict__ dst, int i) {
    float4 v0 = *(const float4*)(src + i);
    float4 v1 = *(const float4*)(src + i + 4);
    ushort4 o0, o1;
    o0.x = f2bf(v0.x); o0.y = f2bf(v0.y); o0.z = f2bf(v0.z); o0.w = f2bf(v0.w);
    o1.x = f2bf(v1.x); o1.y = f2bf(v1.y); o1.z = f2bf(v1.z); o1.w = f2bf(v1.w);
    *(ushort4*)(dst + i) = o0;
    *(ushort4*)(dst + i + 4) = o1;
}

// One launch: x (2048 blks) + Wq/Wk/Wv (512 blks each) + l zero (1 blk).
struct CV { const float* x; unsigned short* xb;
            const float* W[3]; unsigned short* Wb[3]; float* l; };
__global__ __launch_bounds__(256)
void cvt_all(CV a) {
    int b = blockIdx.x, t = threadIdx.x;
    if (b < 2048) {
        cvt8(a.x, a.xb, (b * 256 + t) * 8);
    } else if (b < 3584) {
        int z  = (b - 2048) >> 9;
        int bb = (b - 2048) & 511;
        cvt8(a.W[z], a.Wb[z], (bb * 256 + t) * 8);
    } else {
        float4 zz = {0.f, 0.f, 0.f, 0.f};
        #pragma unroll
        for (int c = 0; c < 4; c++)
            *(float4*)(a.l + t * 16 + c * 4) = zz;
    }
}

// inline-asm ds_read_b128: invisible to the compiler's waitcnt pass (no
// injected vmcnt(0) drains vs in-flight global_load_lds). Ordering is manual.
#define DSR(dst, base, OFF)                                                    \
    asm volatile("ds_read_b128 %0, %1 offset:%2"                               \
                 : "=v"(dst) : "v"(base), "n"(OFF))
#define DSR4(arr, base, O)                                                     \
    do { DSR(arr[0], base, (O));        DSR(arr[1], base, (O) + 1024);         \
         DSR(arr[2], base, (O) + 2048); DSR(arr[3], base, (O) + 3072); } while (0)
#define LGKM(N) asm volatile("s_waitcnt lgkmcnt(" #N ")" ::: "memory")
#define VMC6()  asm volatile("s_waitcnt vmcnt(6)" ::: "memory")
#define SBAR()  asm volatile("s_barrier" ::: "memory")
#define SB0     __builtin_amdgcn_sched_barrier(0)

typedef __attribute__((address_space(3))) char* lds3p;

// ============================================================================
// 256x256 GEMM core (C += A B^T, K = 1024 = 16 tiles of BK=64)
//
// 512 threads = 8 waves (2M x 4N); per-wave output 128x64 (acc[8][4]).
// LDS 128 KiB: A/B x dbuf(tile parity) x (2 K-half units of 256r x 32c=16KB).
// Per K-tile: 4 phases, 16 MFMA each, ONE barrier each (end).
//
// SKEW-PIPELINED schedule (session-best, measured twice: 195.35/193.32us
// total; LOCKED). Phase:
//   STAGE ; vmcnt(6) ; lgkmcnt(0) ; [16 MFMA clean burst] ;
//   issue NEXT phase's ds_reads ; s_barrier
// Reads sit between the MFMA burst and the barrier: waves that finish MFMA
// early issue reads that drain through the LDS pipe WHILE slower waves on
// the CU still run their MFMA tails (cross-wave overlap via barrier skew).
// lgkmcnt(0) at phase top waits only on reads that have had barrier
// rendezvous + peers' tails to drain. MFMA burst contains no waits.
// Trailing reads write only the inactive ping-pong register set.
//
// Stage schedule (hazard-verified per unit):
//   P0: A-kh1(t+1)   P1: B-kh0(t+2)   P2: B-kh1(t+2)   P3: A-kh0(t+2)
// UNIFORM vmcnt(6) after every STAGE: queue holds 4 units (8 insts), so
// vmcnt(6) forces exactly the unit staged 4 phases earlier; every unit is
// forced + barrier'd >= 1 barrier before its first ds_read. Prologue stages
// 7 units; vmcnt(6) there forces tile 0. Tail dummy stages (tau>=16 ->
// tau-2) rewrite identical data: benign. Post-loop lgkmcnt(0) quiesces
// trailing reads before register reuse; epilogue __syncthreads drains vmem.
// ============================================================================
__device__ __forceinline__ void gemm256_core(
    const unsigned short* __restrict__ A, const unsigned short* __restrict__ B,
    int lda, int k_begin, int bm, int bn,
    unsigned short* lds, floatx4 (&acc)[8][4])
{
    const int t    = threadIdx.x;
    const int wave = t >> 6;
    const int lane = t & 63;
    const int wrow = wave >> 2;        // 0..1
    const int wcol = wave & 3;         // 0..3
    const int lm   = lane & 15;
    const int ce8  = (((lane >> 4) ^ ((lm >> 1) & 3)) << 3);   // swizzled chunk (elems)

    // staging: thread t owns rows t>>2 and t>>2 + 128 of the unit
    const int srow = t >> 2;
    const int gsh  = (((t & 3) ^ ((srow >> 1) & 3)) << 3);     // pre-swizzled src chunk
    const unsigned short* srcA = A + (size_t)(bm + srow) * lda + k_begin + gsh;
    const unsigned short* srcB = B + (size_t)(bn + srow) * lda + k_begin + gsh;
    const size_t rstep = (size_t)128 * lda;
    char* ldsc = (char*)lds;
    const int w1k = wave << 10;

    // loop-invariant ds_read base pointers (as3): dbuf/kh/frag strides all in
    // offset immediates (A max 56320, B max 52224 within region -> ok).
    lds3p lp3 = (lds3p)lds;
    lds3p va = lp3 + (((wrow << 7) + lm) * 64 + (ce8 << 1));           // A region
    lds3p vb = lp3 + (65536 + ((wcol << 6) + lm) * 64 + (ce8 << 1));   // B region

#define STAGE(kind, kh, tau) do {                                              \
        int taue_ = (tau) >= 16 ? (tau) - 2 : (tau);  /* dummy rewrites same data */ \
        int ko_ = (taue_ << 6) + ((kh) << 5);                                  \
        unsigned lo_ = ((kind) << 16) + (((tau) & 1) << 15) + ((kh) << 14) + w1k; \
        const unsigned short* s_ = ((kind) ? srcB : srcA) + ko_;               \
        __builtin_amdgcn_global_load_lds(                                      \
            (const __attribute__((address_space(1))) void*)s_,                 \
            (__attribute__((address_space(3))) void*)(ldsc + lo_), 16, 0, 0);  \
        __builtin_amdgcn_global_load_lds(                                      \
            (const __attribute__((address_space(1))) void*)(s_ + rstep),       \
            (__attribute__((address_space(3))) void*)(ldsc + lo_ + 8192), 16, 0, 0); \
    } while (0)

#define MF1(R, AV, BV)                                                         \
    do {                                                                       \
        acc[R][0] = __builtin_amdgcn_mfma_f32_16x16x32_bf16(AV, BV[0], acc[R][0], 0, 0, 0); \
        acc[R][1] = __builtin_amdgcn_mfma_f32_16x16x32_bf16(AV, BV[1], acc[R][1], 0, 0, 0); \
        acc[R][2] = __builtin_amdgcn_mfma_f32_16x16x32_bf16(AV, BV[2], acc[R][2], 0, 0, 0); \
        acc[R][3] = __builtin_amdgcn_mfma_f32_16x16x32_bf16(AV, BV[3], acc[R][3], 0, 0, 0); \
    } while (0)
#define MFMAG(R0, NA, BV)                                                      \
    do { MF1((R0) + 0, NA[0], BV); MF1((R0) + 1, NA[1], BV);                   \
         MF1((R0) + 2, NA[2], BV); MF1((R0) + 3, NA[3], BV); } while (0)

    // prologue: tile0 {B0,A0,B1,A1} + tile1 {B0,B1,A0}; vmcnt(6) forces tile0.
    STAGE(1, 0, 0); STAGE(0, 0, 0); STAGE(1, 1, 0); STAGE(0, 1, 0);
    STAGE(1, 0, 1); STAGE(1, 1, 1); STAGE(0, 0, 1);
    VMC6();
    SBAR();

    constexpr int DB = 32768, KH = 16384;
    short8 na_cur[4], na_nxt[4], b_cur[4], b_nxt[4];
    // preload P0(tile0) operands: A[p0,kh0,ih0], B[p0,kh0]
    DSR4(na_cur, va, 0);
    DSR4(b_cur,  vb, 0);

    // 4 phases of tile TC (parity base PBc); PBn = next tile's parity base.
#define FOURPH(PBc, PBn, TC)                                                   \
    /* ---- P0: rows 0-3, kh0 ---- */                                          \
    STAGE(0, 1, (TC) + 1);                                                     \
    VMC6(); LGKM(0); SB0;                                                      \
    __builtin_amdgcn_s_setprio(1);                                             \
    MFMAG(0, na_cur, b_cur); SB0;                                              \
    __builtin_amdgcn_s_setprio(0);                                             \
    DSR4(na_nxt, va, (PBc) + 4096);      /* A[c,kh0,ih1] for P1 */             \
    SBAR();                                                                    \
    /* ---- P1: rows 4-7, kh0 ---- */                                          \
    STAGE(1, 0, (TC) + 2);                                                     \
    VMC6(); LGKM(0); SB0;                                                      \
    __builtin_amdgcn_s_setprio(1);                                             \
    MFMAG(4, na_nxt, b_cur); SB0;                                              \
    __builtin_amdgcn_s_setprio(0);                                             \
    DSR4(na_cur, va, (PBc) + KH);        /* A[c,kh1,ih0] for P2 */             \
    DSR4(b_nxt,  vb, (PBc) + KH);        /* B[c,kh1] for P2/P3 */              \
    SBAR();                                                                    \
    /* ---- P2: rows 0-3, kh1 ---- */                                          \
    STAGE(1, 1, (TC) + 2);                                                     \
    VMC6(); LGKM(0); SB0;                                                      \
    __builtin_amdgcn_s_setprio(1);                                             \
    MFMAG(0, na_cur, b_nxt); SB0;                                              \
    __builtin_amdgcn_s_setprio(0);                                             \
    DSR4(na_nxt, va, (PBc) + KH + 4096); /* A[c,kh1,ih1] for P3 */             \
    SBAR();                                                                    \
    /* ---- P3: rows 4-7, kh1 ---- */                                          \
    STAGE(0, 0, (TC) + 2);                                                     \
    VMC6(); LGKM(0); SB0;                                                      \
    __builtin_amdgcn_s_setprio(1);                                             \
    MFMAG(4, na_nxt, b_nxt); SB0;                                              \
    __builtin_amdgcn_s_setprio(0);                                             \
    DSR4(na_cur, va, (PBn));             /* A[n,kh0,ih0] for next P0 */        \
    DSR4(b_cur,  vb, (PBn));             /* B[n,kh0] */                        \
    SBAR();

    for (int t2 = 0; t2 < 16; t2 += 2) {
        FOURPH(0, DB, t2);
        FOURPH(DB, 0, t2 + 1);
    }
    LGKM(0);   // drain trailing tail reads before registers are reused
#undef FOURPH
#undef STAGE
#undef MFMAG
#undef MF1
}

// ---- 256x256 tile store via LDS (two 128-row passes, stride 264) -----------
// Scattered 2B epilogue stores trigger L2 write-allocate HBM fetches; staging
// in LDS then streaming full 256B-per-row lines avoids it (verified lineage).
// First __syncthreads drains the in-flight dummy global_load_lds (full drain).
__device__ __forceinline__ void tile_store256(unsigned short* sm, // >= 128*264
                                              floatx4 (&acc)[8][4], float scale, int trans,
                                              unsigned short* __restrict__ C, int ldc,
                                              int rbase, int cbase)
{
    const int t = threadIdx.x, wave = t >> 6, lane = t & 63;
    const int wrow = wave >> 2, wcol = wave & 3;
    const int lm = lane & 15, rq = ((lane >> 4) << 2);
    #pragma unroll
    for (int h = 0; h < 2; h++) {
        __syncthreads();
        if (!trans) {
            if (wrow == h) {
                #pragma unroll
                for (int i = 0; i < 8; i++)
                    #pragma unroll
                    for (int j = 0; j < 4; j++)
                        #pragma unroll
                        for (int r = 0; r < 4; r++)
                            sm[(i * 16 + rq + r) * 264 + wcol * 64 + j * 16 + lm] =
                                f2bf(acc[i][j][r] * scale);
            }
        } else {
            if ((wcol >> 1) == h) {
                #pragma unroll
                for (int i = 0; i < 8; i++)
                    #pragma unroll
                    for (int j = 0; j < 4; j++) {
                        ushort4 v;
                        v.x = f2bf(acc[i][j][0] * scale);
                        v.y = f2bf(acc[i][j][1] * scale);
                        v.z = f2bf(acc[i][j][2] * scale);
                        v.w = f2bf(acc[i][j][3] * scale);
                        *(ushort4*)&sm[((wcol & 1) * 64 + j * 16 + lm) * 264 +
                                       wrow * 128 + i * 16 + rq] = v;
                    }
            }
        }
        __syncthreads();
        #pragma unroll
        for (int p = 0; p < 4; p++) {
            int row = p * 32 + (t >> 4);
            int c0  = (t & 15) * 8;
            *(short8*)&C[(size_t)(rbase + h * 128 + row) * ldc + cbase + c0] =
                *(const short8*)&sm[row * 264 + c0];
            *(short8*)&C[(size_t)(rbase + h * 128 + row) * ldc + cbase + c0 + 128] =
                *(const short8*)&sm[row * 264 + c0 + 128];
        }
    }
}

// ---- fused 3-way projection: {Wq->q(*1/32), Wk->k, Wv->vT} ----------------
struct P3 { const unsigned short* W[3]; unsigned short* O[3]; };
__global__ __launch_bounds__(512, 2)
void proj3(const unsigned short* __restrict__ xb, P3 a) {
    __shared__ __align__(16) unsigned short lds[65536];
    const int lid = blockIdx.x;                 // 0..191
    const int xcd = lid & 7, rem = lid >> 3;
    const int z   = rem >> 3;                   // 0..2
    const int idx = xcd * 8 + (rem & 7);        // 0..63
    const int by = idx >> 2, bx = idx & 3;      // 16 x 4 tiles of 256
    const int bm = by * 256, bn = bx * 256;

    floatx4 acc[8][4];
    #pragma unroll
    for (int i = 0; i < 8; i++)
        #pragma unroll
        for (int j = 0; j < 4; j++) { floatx4 zz = {0.f,0.f,0.f,0.f}; acc[i][j] = zz; }

    gemm256_core(xb, a.W[z], 1024, 0, bm, bn, lds, acc);

    const int trans = (z == 2);
    const float scale = (z == 0) ? 0.03125f : 1.0f;
    tile_store256(lds, acc, scale, trans, a.O[z],
                  trans ? 4096 : 1024, trans ? bn : bm, trans ? bm : bn);
}

// ---- PS-GEMM: P = exp(q k^T) bf16 (scale pre-folded into q), row sums -> l -
__global__ __launch_bounds__(512, 2)
void gemm_ps(const unsigned short* __restrict__ q, const unsigned short* __restrict__ k,
             unsigned short* __restrict__ Pm, float* __restrict__ l) {
    __shared__ __align__(16) unsigned short lds[65536];
    const int lid = blockIdx.x;                 // 0..255 (exactly 1 block/CU)
    const int xcd = lid & 7, r32 = lid >> 3;
    const int by = ((xcd >> 1) << 2) + (r32 & 3);
    const int bx = ((xcd & 1) << 3) + (r32 >> 2);
    const int bm = by * 256, bn = bx * 256;

    floatx4 acc[8][4];
    #pragma unroll
    for (int i = 0; i < 8; i++)
        #pragma unroll
        for (int j = 0; j < 4; j++) { floatx4 zz = {0.f,0.f,0.f,0.f}; acc[i][j] = zz; }

    gemm256_core(q, k, 1024, 0, bm, bn, lds, acc);

    const int lane = threadIdx.x & 63, wave = threadIdx.x >> 6;
    const int wrow = wave >> 2;
    const int lm = lane & 15, rq = ((lane >> 4) << 2);
    #pragma unroll
    for (int i = 0; i < 8; i++) {
        #pragma unroll
        for (int r = 0; r < 4; r++) {
            float rs = 0.f;
            #pragma unroll
            for (int j = 0; j < 4; j++) {
                float e = __expf(acc[i][j][r]);
                acc[i][j][r] = e;
                rs += e;
            }
            rs += __shfl_xor(rs, 1);
            rs += __shfl_xor(rs, 2);
            rs += __shfl_xor(rs, 4);
            rs += __shfl_xor(rs, 8);
            if (lm == 0) atomicAdd(l + bm + wrow * 128 + i * 16 + rq + r, rs);
        }
    }
    tile_store256(lds, acc, 1.0f, 0, Pm, 4096, bm, bn);
}

// ---- O-GEMM split-K=4: 256x256 tiles, bf16 partials ------------------------
__global__ __launch_bounds__(512, 2)
void gemm_osplit(const unsigned short* __restrict__ Pm, const unsigned short* __restrict__ vT,
                 unsigned short* __restrict__ Opart) {
    __shared__ __align__(16) unsigned short lds[65536];
    const int lid = blockIdx.x;                 // 0..255
    const int xcd = lid & 7, r32 = lid >> 3;
    const int z   = r32 & 3;                    // K quarter
    const int idx = (r32 >> 2) * 8 + xcd;       // 0..63
    const int by = idx >> 2, bx = idx & 3;      // 16 x 4 tiles

    floatx4 acc[8][4];
    #pragma unroll
    for (int i = 0; i < 8; i++)
        #pragma unroll
        for (int j = 0; j < 4; j++) { floatx4 zz = {0.f,0.f,0.f,0.f}; acc[i][j] = zz; }

    gemm256_core(Pm, vT, 4096, z * 1024, by * 256, bx * 256, lds, acc);

    tile_store256(lds, acc, 1.0f, 0, Opart + (size_t)z * (4096 * 1024), 1024,
                  by * 256, bx * 256);
}

// ---- reduce 4 bf16 split-K partials + apply deferred 1/l row scale ---------
__global__ __launch_bounds__(256)
void reduce_scale(const unsigned short* __restrict__ Op, const float* __restrict__ l,
                  float* __restrict__ out) {
    int i = (blockIdx.x * 256 + threadIdx.x) * 4;
    ushort4 a = *(const ushort4*)(Op + i);
    ushort4 b = *(const ushort4*)(Op + 4194304 + i);
    ushort4 c = *(const ushort4*)(Op + 8388608 + i);
    ushort4 d = *(const ushort4*)(Op + 12582912 + i);
    float inv = 1.0f / l[i >> 10];
    float4 o;
    o.x = (bf2f(a.x) + bf2f(b.x) + bf2f(c.x) + bf2f(d.x)) * inv;
    o.y = (bf2f(a.y) + bf2f(b.y) + bf2f(c.y) + bf2f(d.y)) * inv;
    o.z = (bf2f(a.z) + bf2f(b.z) + bf2f(c.z) + bf2f(d.z)) * inv;
    o.w = (bf2f(a.w) + bf2f(b.w) + bf2f(c.w) + bf2f(d.w)) * inv;
    *(float4*)(out + i) = o;
}

// ---------------- driver -----------------------------------------------
extern "C" void kernel_launch(void* const* d_in, const int* in_sizes, int n_in,
                              void* d_out, int out_size, void* d_ws, size_t ws_size,
                              hipStream_t stream) {
    const float* x  = (const float*)d_in[0];
    const float* Wq = (const float*)d_in[1];
    const float* Wk = (const float*)d_in[2];
    const float* Wv = (const float*)d_in[3];
    float* out = (float*)d_out;

    char* ws = (char*)d_ws;
    const size_t MB = 1u << 20;
    unsigned short* vTb = (unsigned short*)(ws);             //  0..8   bf16 [D x SEQ]
    unsigned short* xb  = (unsigned short*)(ws + 8 * MB);    //  8..16
    unsigned short* Wqb = (unsigned short*)(ws + 16 * MB);   // 16..18
    unsigned short* Wkb = (unsigned short*)(ws + 18 * MB);   // 18..20
    unsigned short* Wvb = (unsigned short*)(ws + 20 * MB);   // 20..22
    unsigned short* qb  = (unsigned short*)(ws + 22 * MB);   // 22..30
    unsigned short* kb  = (unsigned short*)(ws + 30 * MB);   // 30..38
    unsigned short* P   = (unsigned short*)(ws + 40 * MB);   // 40..72  bf16 [SEQ x SEQ]
    float*          l   = (float*)(ws + 72 * MB);            // 72..72.016 row sums
    // Opart aliases xb/W/qb/kb (all dead once gemm_ps has run): 4 x 8 MB
    unsigned short* Opart = (unsigned short*)(ws + 8 * MB);  //  8..40

    dim3 b256(256), b512(512);
    CV cv = {x, xb, {Wq, Wk, Wv}, {Wqb, Wkb, Wvb}, l};
    cvt_all<<<dim3(3585), b256, 0, stream>>>(cv);

    // q(*1/32)/k/vT: 256x256 tiles, skew-pipelined core, 192 blocks
    P3 p3 = {{Wqb, Wkb, Wvb}, {qb, kb, vTb}};
    proj3<<<dim3(192), b512, 0, stream>>>(xb, p3);

    // P = exp(q k^T) bf16 + row sums l (256 blocks = 1/CU)
    gemm_ps<<<dim3(256), b512, 0, stream>>>(qb, kb, P, l);

    // O partials bf16, split-K=4 (256 blocks)
    gemm_osplit<<<dim3(256), b512, 0, stream>>>(P, vTb, Opart);

    // out = (sum of 4 partials) / l[row]
    reduce_scale<<<dim3(4096), b256, 0, stream>>>(Opart, l, out);
}

// Round 13
// 189.620 us; speedup vs baseline: 1.0438x; 1.0438x over previous
//
#include <hip/hip_runtime.h>
#include <hip/hip_bf16.h>
#include <math.h>

typedef __attribute__((ext_vector_type(8))) short short8;
typedef __attribute__((ext_vector_type(4))) float floatx4;

static __device__ __forceinline__ unsigned short f2bf(float f) {
    union { float f; unsigned int u; } a; a.f = f;
    unsigned int u = a.u;
    return (unsigned short)((u + 0x7FFFu + ((u >> 16) & 1u)) >> 16);
}
static __device__ __forceinline__ float bf2f(unsigned short h) {
    union { unsigned int u; float f; } a; a.u = ((unsigned int)h) << 16;
    return a.f;
}

// ---------------- fp32 -> bf16 convert, 8 elems/thread ----------------
static __device__ __forceinline__ void cvt8(const float* __restrict__ src,
                                            unsigned short* __restrict__ dst, int i) {
    float4 v0 = *(const float4*)(src + i);
    float4 v1 = *(const float4*)(src + i + 4);
    ushort4 o0, o1;
    o0.x = f2bf(v0.x); o0.y = f2bf(v0.y); o0.z = f2bf(v0.z); o0.w = f2bf(v0.w);
    o1.x = f2bf(v1.x); o1.y = f2bf(v1.y); o1.z = f2bf(v1.z); o1.w = f2bf(v1.w);
    *(ushort4*)(dst + i) = o0;
    *(ushort4*)(dst + i + 4) = o1;
}

// One launch: x (2048 blks) + Wq/Wk/Wv (512 blks each) + l zero (1 blk).
struct CV { const float* x; unsigned short* xb;
            const float* W[3]; unsigned short* Wb[3]; float* l; };
__global__ __launch_bounds__(256)
void cvt_all(CV a) {
    int b = blockIdx.x, t = threadIdx.x;
    if (b < 2048) {
        cvt8(a.x, a.xb, (b * 256 + t) * 8);
    } else if (b < 3584) {
        int z  = (b - 2048) >> 9;
        int bb = (b - 2048) & 511;
        cvt8(a.W[z], a.Wb[z], (bb * 256 + t) * 8);
    } else {
        float4 zz = {0.f, 0.f, 0.f, 0.f};
        #pragma unroll
        for (int c = 0; c < 4; c++)
            *(float4*)(a.l + t * 16 + c * 4) = zz;
    }
}

// inline-asm ds_read_b128: invisible to the compiler's waitcnt pass (no
// injected vmcnt(0) drains vs in-flight global_load_lds). Ordering is manual.
#define DSR(dst, base, OFF)                                                    \
    asm volatile("ds_read_b128 %0, %1 offset:%2"                               \
                 : "=v"(dst) : "v"(base), "n"(OFF))
#define DSR4(arr, base, O)                                                     \
    do { DSR(arr[0], base, (O));        DSR(arr[1], base, (O) + 1024);         \
         DSR(arr[2], base, (O) + 2048); DSR(arr[3], base, (O) + 3072); } while (0)
#define LGKM(N) asm volatile("s_waitcnt lgkmcnt(" #N ")" ::: "memory")
#define VMC6()  asm volatile("s_waitcnt vmcnt(6)" ::: "memory")
#define SBAR()  asm volatile("s_barrier" ::: "memory")
#define SB0     __builtin_amdgcn_sched_barrier(0)

typedef __attribute__((address_space(3))) char* lds3p;

// ============================================================================
// 256x256 GEMM core (C += A B^T, K = 1024 = 16 tiles of BK=64)
//
// 512 threads = 8 waves (2M x 4N); per-wave output 128x64 (acc[8][4]).
// LDS 128 KiB: A/B x dbuf(tile parity) x (2 K-half units of 256r x 32c=16KB).
// Per K-tile: 4 phases, 16 MFMA each, ONE barrier each (end).
//
// SKEW-PIPELINED schedule (session-best, measured 3x: 193.3/195.4/197.9us
// total; LOCKED). Phase:
//   STAGE ; vmcnt(6) ; lgkmcnt(0) ; [16 MFMA clean burst] ;
//   issue NEXT phase's ds_reads ; s_barrier
// Reads sit between the MFMA burst and the barrier: waves that finish MFMA
// early issue reads that drain through the LDS pipe WHILE slower waves on
// the CU still run their MFMA tails (cross-wave overlap via barrier skew).
// lgkmcnt(0) at phase top waits only on reads that have had barrier
// rendezvous + peers' tails to drain. MFMA burst contains no waits.
// Trailing reads write only the inactive ping-pong register set.
//
// Stage schedule (hazard-verified per unit):
//   P0: A-kh1(t+1)   P1: B-kh0(t+2)   P2: B-kh1(t+2)   P3: A-kh0(t+2)
// UNIFORM vmcnt(6) after every STAGE: queue holds 4 units (8 insts), so
// vmcnt(6) forces exactly the unit staged 4 phases earlier; every unit is
// forced + barrier'd >= 1 barrier before its first ds_read. Prologue stages
// 7 units; vmcnt(6) there forces tile 0. Tail dummy stages (tau>=16 ->
// tau-2) rewrite identical data: benign. Post-loop lgkmcnt(0) quiesces
// trailing reads before register reuse; epilogue __syncthreads drains vmem.
// ============================================================================
__device__ __forceinline__ void gemm256_core(
    const unsigned short* __restrict__ A, const unsigned short* __restrict__ B,
    int lda, int k_begin, int bm, int bn,
    unsigned short* lds, floatx4 (&acc)[8][4])
{
    const int t    = threadIdx.x;
    const int wave = t >> 6;
    const int lane = t & 63;
    const int wrow = wave >> 2;        // 0..1
    const int wcol = wave & 3;         // 0..3
    const int lm   = lane & 15;
    const int ce8  = (((lane >> 4) ^ ((lm >> 1) & 3)) << 3);   // swizzled chunk (elems)

    // staging: thread t owns rows t>>2 and t>>2 + 128 of the unit
    const int srow = t >> 2;
    const int gsh  = (((t & 3) ^ ((srow >> 1) & 3)) << 3);     // pre-swizzled src chunk
    const unsigned short* srcA = A + (size_t)(bm + srow) * lda + k_begin + gsh;
    const unsigned short* srcB = B + (size_t)(bn + srow) * lda + k_begin + gsh;
    const size_t rstep = (size_t)128 * lda;
    char* ldsc = (char*)lds;
    const int w1k = wave << 10;

    // loop-invariant ds_read base pointers (as3): dbuf/kh/frag strides all in
    // offset immediates (A max 56320, B max 52224 within region -> ok).
    lds3p lp3 = (lds3p)lds;
    lds3p va = lp3 + (((wrow << 7) + lm) * 64 + (ce8 << 1));           // A region
    lds3p vb = lp3 + (65536 + ((wcol << 6) + lm) * 64 + (ce8 << 1));   // B region

#define STAGE(kind, kh, tau) do {                                              \
        int taue_ = (tau) >= 16 ? (tau) - 2 : (tau);  /* dummy rewrites same data */ \
        int ko_ = (taue_ << 6) + ((kh) << 5);                                  \
        unsigned lo_ = ((kind) << 16) + (((tau) & 1) << 15) + ((kh) << 14) + w1k; \
        const unsigned short* s_ = ((kind) ? srcB : srcA) + ko_;               \
        __builtin_amdgcn_global_load_lds(                                      \
            (const __attribute__((address_space(1))) void*)s_,                 \
            (__attribute__((address_space(3))) void*)(ldsc + lo_), 16, 0, 0);  \
        __builtin_amdgcn_global_load_lds(                                      \
            (const __attribute__((address_space(1))) void*)(s_ + rstep),       \
            (__attribute__((address_space(3))) void*)(ldsc + lo_ + 8192), 16, 0, 0); \
    } while (0)

#define MF1(R, AV, BV)                                                         \
    do {                                                                       \
        acc[R][0] = __builtin_amdgcn_mfma_f32_16x16x32_bf16(AV, BV[0], acc[R][0], 0, 0, 0); \
        acc[R][1] = __builtin_amdgcn_mfma_f32_16x16x32_bf16(AV, BV[1], acc[R][1], 0, 0, 0); \
        acc[R][2] = __builtin_amdgcn_mfma_f32_16x16x32_bf16(AV, BV[2], acc[R][2], 0, 0, 0); \
        acc[R][3] = __builtin_amdgcn_mfma_f32_16x16x32_bf16(AV, BV[3], acc[R][3], 0, 0, 0); \
    } while (0)
#define MFMAG(R0, NA, BV)                                                      \
    do { MF1((R0) + 0, NA[0], BV); MF1((R0) + 1, NA[1], BV);                   \
         MF1((R0) + 2, NA[2], BV); MF1((R0) + 3, NA[3], BV); } while (0)

    // prologue: tile0 {B0,A0,B1,A1} + tile1 {B0,B1,A0}; vmcnt(6) forces tile0.
    STAGE(1, 0, 0); STAGE(0, 0, 0); STAGE(1, 1, 0); STAGE(0, 1, 0);
    STAGE(1, 0, 1); STAGE(1, 1, 1); STAGE(0, 0, 1);
    VMC6();
    SBAR();

    constexpr int DB = 32768, KH = 16384;
    short8 na_cur[4], na_nxt[4], b_cur[4], b_nxt[4];
    // preload P0(tile0) operands: A[p0,kh0,ih0], B[p0,kh0]
    DSR4(na_cur, va, 0);
    DSR4(b_cur,  vb, 0);

    // 4 phases of tile TC (parity base PBc); PBn = next tile's parity base.
#define FOURPH(PBc, PBn, TC)                                                   \
    /* ---- P0: rows 0-3, kh0 ---- */                                          \
    STAGE(0, 1, (TC) + 1);                                                     \
    VMC6(); LGKM(0); SB0;                                                      \
    __builtin_amdgcn_s_setprio(1);                                             \
    MFMAG(0, na_cur, b_cur); SB0;                                              \
    __builtin_amdgcn_s_setprio(0);                                             \
    DSR4(na_nxt, va, (PBc) + 4096);      /* A[c,kh0,ih1] for P1 */             \
    SBAR();                                                                    \
    /* ---- P1: rows 4-7, kh0 ---- */                                          \
    STAGE(1, 0, (TC) + 2);                                                     \
    VMC6(); LGKM(0); SB0;                                                      \
    __builtin_amdgcn_s_setprio(1);                                             \
    MFMAG(4, na_nxt, b_cur); SB0;                                              \
    __builtin_amdgcn_s_setprio(0);                                             \
    DSR4(na_cur, va, (PBc) + KH);        /* A[c,kh1,ih0] for P2 */             \
    DSR4(b_nxt,  vb, (PBc) + KH);        /* B[c,kh1] for P2/P3 */              \
    SBAR();                                                                    \
    /* ---- P2: rows 0-3, kh1 ---- */                                          \
    STAGE(1, 1, (TC) + 2);                                                     \
    VMC6(); LGKM(0); SB0;                                                      \
    __builtin_amdgcn_s_setprio(1);                                             \
    MFMAG(0, na_cur, b_nxt); SB0;                                              \
    __builtin_amdgcn_s_setprio(0);                                             \
    DSR4(na_nxt, va, (PBc) + KH + 4096); /* A[c,kh1,ih1] for P3 */             \
    SBAR();                                                                    \
    /* ---- P3: rows 4-7, kh1 ---- */                                          \
    STAGE(0, 0, (TC) + 2);                                                     \
    VMC6(); LGKM(0); SB0;                                                      \
    __builtin_amdgcn_s_setprio(1);                                             \
    MFMAG(4, na_nxt, b_nxt); SB0;                                              \
    __builtin_amdgcn_s_setprio(0);                                             \
    DSR4(na_cur, va, (PBn));             /* A[n,kh0,ih0] for next P0 */        \
    DSR4(b_cur,  vb, (PBn));             /* B[n,kh0] */                        \
    SBAR();

    for (int t2 = 0; t2 < 16; t2 += 2) {
        FOURPH(0, DB, t2);
        FOURPH(DB, 0, t2 + 1);
    }
    LGKM(0);   // drain trailing tail reads before registers are reused
#undef FOURPH
#undef STAGE
#undef MFMAG
#undef MF1
}

// ---- 256x256 tile store via LDS (two 128-row passes, stride 264) -----------
// Scattered 2B epilogue stores trigger L2 write-allocate HBM fetches; staging
// in LDS then streaming full 256B-per-row lines avoids it (verified lineage).
// First __syncthreads drains the in-flight dummy global_load_lds (full drain).
__device__ __forceinline__ void tile_store256(unsigned short* sm, // >= 128*264
                                              floatx4 (&acc)[8][4], float scale, int trans,
                                              unsigned short* __restrict__ C, int ldc,
                                              int rbase, int cbase)
{
    const int t = threadIdx.x, wave = t >> 6, lane = t & 63;
    const int wrow = wave >> 2, wcol = wave & 3;
    const int lm = lane & 15, rq = ((lane >> 4) << 2);
    #pragma unroll
    for (int h = 0; h < 2; h++) {
        __syncthreads();
        if (!trans) {
            if (wrow == h) {
                #pragma unroll
                for (int i = 0; i < 8; i++)
                    #pragma unroll
                    for (int j = 0; j < 4; j++)
                        #pragma unroll
                        for (int r = 0; r < 4; r++)
                            sm[(i * 16 + rq + r) * 264 + wcol * 64 + j * 16 + lm] =
                                f2bf(acc[i][j][r] * scale);
            }
        } else {
            if ((wcol >> 1) == h) {
                #pragma unroll
                for (int i = 0; i < 8; i++)
                    #pragma unroll
                    for (int j = 0; j < 4; j++) {
                        ushort4 v;
                        v.x = f2bf(acc[i][j][0] * scale);
                        v.y = f2bf(acc[i][j][1] * scale);
                        v.z = f2bf(acc[i][j][2] * scale);
                        v.w = f2bf(acc[i][j][3] * scale);
                        *(ushort4*)&sm[((wcol & 1) * 64 + j * 16 + lm) * 264 +
                                       wrow * 128 + i * 16 + rq] = v;
                    }
            }
        }
        __syncthreads();
        #pragma unroll
        for (int p = 0; p < 4; p++) {
            int row = p * 32 + (t >> 4);
            int c0  = (t & 15) * 8;
            *(short8*)&C[(size_t)(rbase + h * 128 + row) * ldc + cbase + c0] =
                *(const short8*)&sm[row * 264 + c0];
            *(short8*)&C[(size_t)(rbase + h * 128 + row) * ldc + cbase + c0 + 128] =
                *(const short8*)&sm[row * 264 + c0 + 128];
        }
    }
}

// ---- fused 3-way projection: {Wq->q(*1/32), Wk->k, Wv->vT} ----------------
struct P3 { const unsigned short* W[3]; unsigned short* O[3]; };
__global__ __launch_bounds__(512, 2)
void proj3(const unsigned short* __restrict__ xb, P3 a) {
    __shared__ __align__(16) unsigned short lds[65536];
    const int lid = blockIdx.x;                 // 0..191
    const int xcd = lid & 7, rem = lid >> 3;
    const int z   = rem >> 3;                   // 0..2
    const int idx = xcd * 8 + (rem & 7);        // 0..63
    const int by = idx >> 2, bx = idx & 3;      // 16 x 4 tiles of 256
    const int bm = by * 256, bn = bx * 256;

    floatx4 acc[8][4];
    #pragma unroll
    for (int i = 0; i < 8; i++)
        #pragma unroll
        for (int j = 0; j < 4; j++) { floatx4 zz = {0.f,0.f,0.f,0.f}; acc[i][j] = zz; }

    gemm256_core(xb, a.W[z], 1024, 0, bm, bn, lds, acc);

    const int trans = (z == 2);
    const float scale = (z == 0) ? 0.03125f : 1.0f;
    tile_store256(lds, acc, scale, trans, a.O[z],
                  trans ? 4096 : 1024, trans ? bn : bm, trans ? bm : bn);
}

// ---- PS-GEMM: P = exp(q k^T) bf16 (scale pre-folded into q), row sums -> l -
__global__ __launch_bounds__(512, 2)
void gemm_ps(const unsigned short* __restrict__ q, const unsigned short* __restrict__ k,
             unsigned short* __restrict__ Pm, float* __restrict__ l) {
    __shared__ __align__(16) unsigned short lds[65536];
    const int lid = blockIdx.x;                 // 0..255 (exactly 1 block/CU)
    const int xcd = lid & 7, r32 = lid >> 3;
    const int by = ((xcd >> 1) << 2) + (r32 & 3);
    const int bx = ((xcd & 1) << 3) + (r32 >> 2);
    const int bm = by * 256, bn = bx * 256;

    floatx4 acc[8][4];
    #pragma unroll
    for (int i = 0; i < 8; i++)
        #pragma unroll
        for (int j = 0; j < 4; j++) { floatx4 zz = {0.f,0.f,0.f,0.f}; acc[i][j] = zz; }

    gemm256_core(q, k, 1024, 0, bm, bn, lds, acc);

    const int lane = threadIdx.x & 63, wave = threadIdx.x >> 6;
    const int wrow = wave >> 2;
    const int lm = lane & 15, rq = ((lane >> 4) << 2);
    #pragma unroll
    for (int i = 0; i < 8; i++) {
        #pragma unroll
        for (int r = 0; r < 4; r++) {
            float rs = 0.f;
            #pragma unroll
            for (int j = 0; j < 4; j++) {
                float e = __expf(acc[i][j][r]);
                acc[i][j][r] = e;
                rs += e;
            }
            rs += __shfl_xor(rs, 1);
            rs += __shfl_xor(rs, 2);
            rs += __shfl_xor(rs, 4);
            rs += __shfl_xor(rs, 8);
            if (lm == 0) atomicAdd(l + bm + wrow * 128 + i * 16 + rq + r, rs);
        }
    }
    tile_store256(lds, acc, 1.0f, 0, Pm, 4096, bm, bn);
}

// ---- O-GEMM split-K=4: 256x256 tiles, bf16 partials ------------------------
// r13: XCD-locality remap. The 4 bx-blocks of one (by,z) pair read the SAME
// 8 MB P-panel stream; old mapping put them on 4 different XCDs (bx was a
// pure function of xcd) -> 4x HBM fetch of P. New mapping co-locates each
// (by,z) quad on one XCD (2 by-values + 4 z per XCD; instantaneous K-window
// working set ~2 MB << 4 MB L2) so one fetch serves four blocks.
// Bijective: (xcd 0..7, p 0..7, bx 0..3) <-> lid; by=2*xcd+(p>>2) covers
// 0..15, z=p&3 covers 0..3, bx covers 0..3 -> 16x4x4 = 256 distinct tiles.
__global__ __launch_bounds__(512, 2)
void gemm_osplit(const unsigned short* __restrict__ Pm, const unsigned short* __restrict__ vT,
                 unsigned short* __restrict__ Opart) {
    __shared__ __align__(16) unsigned short lds[65536];
    const int lid = blockIdx.x;                 // 0..255
    const int xcd = lid & 7;
    const int s   = lid >> 3;                   // 0..31
    const int p   = s >> 2;                     // pair index within XCD, 0..7
    const int bx  = s & 3;                      // column tile (vT panel)
    const int by  = 2 * xcd + (p >> 2);         // row tile 0..15 (P panel)
    const int z   = p & 3;                      // K quarter

    floatx4 acc[8][4];
    #pragma unroll
    for (int i = 0; i < 8; i++)
        #pragma unroll
        for (int j = 0; j < 4; j++) { floatx4 zz = {0.f,0.f,0.f,0.f}; acc[i][j] = zz; }

    gemm256_core(Pm, vT, 4096, z * 1024, by * 256, bx * 256, lds, acc);

    tile_store256(lds, acc, 1.0f, 0, Opart + (size_t)z * (4096 * 1024), 1024,
                  by * 256, bx * 256);
}

// ---- reduce 4 bf16 split-K partials + apply deferred 1/l row scale ---------
__global__ __launch_bounds__(256)
void reduce_scale(const unsigned short* __restrict__ Op, const float* __restrict__ l,
                  float* __restrict__ out) {
    int i = (blockIdx.x * 256 + threadIdx.x) * 4;
    ushort4 a = *(const ushort4*)(Op + i);
    ushort4 b = *(const ushort4*)(Op + 4194304 + i);
    ushort4 c = *(const ushort4*)(Op + 8388608 + i);
    ushort4 d = *(const ushort4*)(Op + 12582912 + i);
    float inv = 1.0f / l[i >> 10];
    float4 o;
    o.x = (bf2f(a.x) + bf2f(b.x) + bf2f(c.x) + bf2f(d.x)) * inv;
    o.y = (bf2f(a.y) + bf2f(b.y) + bf2f(c.y) + bf2f(d.y)) * inv;
    o.z = (bf2f(a.z) + bf2f(b.z) + bf2f(c.z) + bf2f(d.z)) * inv;
    o.w = (bf2f(a.w) + bf2f(b.w) + bf2f(c.w) + bf2f(d.w)) * inv;
    *(float4*)(out + i) = o;
}

// ---------------- driver -----------------------------------------------
extern "C" void kernel_launch(void* const* d_in, const int* in_sizes, int n_in,
                              void* d_out, int out_size, void* d_ws, size_t ws_size,
                              hipStream_t stream) {
    const float* x  = (const float*)d_in[0];
    const float* Wq = (const float*)d_in[1];
    const float* Wk = (const float*)d_in[2];
    const float* Wv = (const float*)d_in[3];
    float* out = (float*)d_out;

    char* ws = (char*)d_ws;
    const size_t MB = 1u << 20;
    unsigned short* vTb = (unsigned short*)(ws);             //  0..8   bf16 [D x SEQ]
    unsigned short* xb  = (unsigned short*)(ws + 8 * MB);    //  8..16
    unsigned short* Wqb = (unsigned short*)(ws + 16 * MB);   // 16..18
    unsigned short* Wkb = (unsigned short*)(ws + 18 * MB);   // 18..20
    unsigned short* Wvb = (unsigned short*)(ws + 20 * MB);   // 20..22
    unsigned short* qb  = (unsigned short*)(ws + 22 * MB);   // 22..30
    unsigned short* kb  = (unsigned short*)(ws + 30 * MB);   // 30..38
    unsigned short* P   = (unsigned short*)(ws + 40 * MB);   // 40..72  bf16 [SEQ x SEQ]
    float*          l   = (float*)(ws + 72 * MB);            // 72..72.016 row sums
    // Opart aliases xb/W/qb/kb (all dead once gemm_ps has run): 4 x 8 MB
    unsigned short* Opart = (unsigned short*)(ws + 8 * MB);  //  8..40

    dim3 b256(256), b512(512);
    CV cv = {x, xb, {Wq, Wk, Wv}, {Wqb, Wkb, Wvb}, l};
    cvt_all<<<dim3(3585), b256, 0, stream>>>(cv);

    // q(*1/32)/k/vT: 256x256 tiles, skew-pipelined core, 192 blocks
    P3 p3 = {{Wqb, Wkb, Wvb}, {qb, kb, vTb}};
    proj3<<<dim3(192), b512, 0, stream>>>(xb, p3);

    // P = exp(q k^T) bf16 + row sums l (256 blocks = 1/CU)
    gemm_ps<<<dim3(256), b512, 0, stream>>>(qb, kb, P, l);

    // O partials bf16, split-K=4 (256 blocks, XCD-colocated P-quads)
    gemm_osplit<<<dim3(256), b512, 0, stream>>>(P, vTb, Opart);

    // out = (sum of 4 partials) / l[row]
    reduce_scale<<<dim3(4096), b256, 0, stream>>>(Opart, l, out);
}